// Round 6
// baseline (247.051 us; speedup 1.0000x reference)
//
#include <hip/hip_runtime.h>

#define BB 16
#define CH 256
#define NH 4
#define DH 64
#define NN 1024

typedef _Float16 f16x8 __attribute__((ext_vector_type(8)));
typedef float f32x4 __attribute__((ext_vector_type(4)));

__device__ __forceinline__ unsigned short f2h(float x) {
    _Float16 h = (_Float16)x;
    return __builtin_bit_cast(unsigned short, h);
}

// ---------------- W -> fp16 hi/lo ----------------
__global__ __launch_bounds__(256) void prep_kernel(
    const float* __restrict__ Wq, const float* __restrict__ Wk, const float* __restrict__ Wv,
    unsigned short* __restrict__ Wh, unsigned short* __restrict__ Wl)
{
    int idx = blockIdx.x * 256 + threadIdx.x;   // 3*CH*CH = 196608
    if (idx >= 3 * CH * CH) return;
    int p = idx >> 16, oc = idx & 65535;
    const float* W = (p == 0) ? Wq : ((p == 1) ? Wk : Wv);
    float w = W[oc];
    _Float16 h = (_Float16)w;
    Wh[idx] = __builtin_bit_cast(unsigned short, h);
    Wl[idx] = f2h(w - (float)h);
}

// ---------------- x fp32 [b][c][n] -> xT fp16 [b][n][c] ----------------
__global__ __launch_bounds__(256) void xt_kernel(
    const float* __restrict__ x, unsigned short* __restrict__ xT)
{
    const int b = blockIdx.z, c0 = blockIdx.y * 32, n0 = blockIdx.x * 32;
    __shared__ float T[32][33];
    const int t = threadIdx.x;
    {
        int c = t >> 3, n4 = (t & 7) * 4;
        float4 v4 = *(const float4*)&x[((size_t)b * CH + c0 + c) * NN + n0 + n4];
        T[c][n4 + 0] = v4.x; T[c][n4 + 1] = v4.y;
        T[c][n4 + 2] = v4.z; T[c][n4 + 3] = v4.w;
    }
    __syncthreads();
    {
        int n = t >> 3, c4 = (t & 7) * 4;
        ushort4 o;
        o.x = f2h(T[c4 + 0][n]); o.y = f2h(T[c4 + 1][n]);
        o.z = f2h(T[c4 + 2][n]); o.w = f2h(T[c4 + 3][n]);
        *(ushort4*)&xT[((size_t)b * NN + n0 + n) * CH + c0 + c4] = o;
    }
}

// ---------------- pos^T fp16: pT[h][n][d] ----------------
__global__ __launch_bounds__(256) void pos_kernel(
    const float* __restrict__ rel_h, const float* __restrict__ rel_w,
    unsigned short* __restrict__ pT)
{
    int idx = blockIdx.x * 256 + threadIdx.x;     // NH*NN*DH = 262144
    if (idx >= NH * NN * DH) return;
    int d = idx & 63, n = (idx >> 6) & (NN - 1), h = idx >> 16;
    float val = rel_w[(h * DH + d) * 32 + (n >> 5)] + rel_h[(h * DH + d) * 32 + (n & 31)];
    pT[idx] = f2h(val);
}

// ---------------- projection via fp16 MFMA (W hi/lo 2-pass) ----------------
__global__ __launch_bounds__(256) void proj_kernel(
    const unsigned short* __restrict__ xT,
    const unsigned short* __restrict__ Wh, const unsigned short* __restrict__ Wl,
    const float* __restrict__ bq, const float* __restrict__ bk, const float* __restrict__ bv,
    unsigned short* __restrict__ qT, unsigned short* __restrict__ kT,
    unsigned short* __restrict__ vH)
{
    const int bz = blockIdx.z;
    const int b = bz / 3, p = bz % 3;
    const int n0 = blockIdx.x * 64;
    const int o0 = blockIdx.y * 64;
    const float* bias = (p == 0) ? bq : ((p == 1) ? bk : bv);

    __shared__ __align__(16) unsigned short Xs[64][72];
    __shared__ __align__(16) unsigned short Whs[64][72];
    __shared__ __align__(16) unsigned short Wls[64][72];

    const int tid = threadIdx.x;
    const int wid = tid >> 6, lane = tid & 63;
    const int g = lane >> 4, lr = lane & 15;

    const unsigned short* xb  = xT + (size_t)b * NN * CH;
    const unsigned short* Whp = Wh + (size_t)p * CH * CH;
    const unsigned short* Wlp = Wl + (size_t)p * CH * CH;

    const f32x4 z4 = {0.f, 0.f, 0.f, 0.f};
    f32x4 acc[4] = {z4, z4, z4, z4};

    for (int cs = 0; cs < 4; ++cs) {
        const int c0 = cs * 64;
        __syncthreads();
        #pragma unroll
        for (int rep = 0; rep < 2; ++rep) {
            int f = rep * 256 + tid;
            int r = f >> 3, s = f & 7;
            *(uint4*)&Xs[r][s * 8]  = *(const uint4*)&xb[(size_t)(n0 + r) * CH + c0 + s * 8];
            *(uint4*)&Whs[r][s * 8] = *(const uint4*)&Whp[(size_t)(o0 + r) * CH + c0 + s * 8];
            *(uint4*)&Wls[r][s * 8] = *(const uint4*)&Wlp[(size_t)(o0 + r) * CH + c0 + s * 8];
        }
        __syncthreads();
        #pragma unroll
        for (int ks = 0; ks < 2; ++ks) {
            f16x8 ah = *(const f16x8*)&Whs[wid * 16 + lr][ks * 32 + g * 8];
            f16x8 al = *(const f16x8*)&Wls[wid * 16 + lr][ks * 32 + g * 8];
            #pragma unroll
            for (int fc = 0; fc < 4; ++fc) {
                f16x8 bx = *(const f16x8*)&Xs[fc * 16 + lr][ks * 32 + g * 8];
                acc[fc] = __builtin_amdgcn_mfma_f32_16x16x32_f16(ah, bx, acc[fc], 0, 0, 0);
                acc[fc] = __builtin_amdgcn_mfma_f32_16x16x32_f16(al, bx, acc[fc], 0, 0, 0);
            }
        }
    }

    float bb[4];
    #pragma unroll
    for (int rr = 0; rr < 4; ++rr) bb[rr] = bias[o0 + wid * 16 + g * 4 + rr];

    if (p < 2) {
        const float scale = (p == 0) ? 1.44269504088896f : 1.0f;   // fold log2e into q
        __syncthreads();
        unsigned short (*Os)[72] = Whs;     // reuse as [n-local][o-local]
        #pragma unroll
        for (int fc = 0; fc < 4; ++fc)
            #pragma unroll
            for (int rr = 0; rr < 4; ++rr)
                Os[fc * 16 + lr][wid * 16 + g * 4 + rr] = f2h((acc[fc][rr] + bb[rr]) * scale);
        __syncthreads();
        unsigned short* dst = ((p == 0) ? qT : kT) + ((size_t)(b * NH + blockIdx.y) * NN + n0) * DH;
        #pragma unroll
        for (int rep = 0; rep < 2; ++rep) {
            int f = rep * 256 + tid;
            int r = f >> 3, s = f & 7;
            *(uint4*)&dst[(size_t)r * DH + s * 8] = *(const uint4*)&Os[r][s * 8];
        }
    } else {
        unsigned short* dv = vH + (size_t)b * CH * NN;
        #pragma unroll
        for (int fc = 0; fc < 4; ++fc)
            #pragma unroll
            for (int rr = 0; rr < 4; ++rr) {
                int o = o0 + wid * 16 + g * 4 + rr;
                dv[(size_t)o * NN + n0 + fc * 16 + lr] = f2h(acc[fc][rr] + bb[rr]);
            }
    }
}

// ---------------- fused flash attention, fp16 MFMA, BARRIER-FREE main loop ----------------
// All K-ext/V fragments read directly from global (L2-resident per XCD after swizzle:
// 8 (b,h) x 384KB = 3MB per 4MB XCD-L2). No LDS staging, no __syncthreads in loop;
// waves fully independent -> no vmcnt-drain stalls (R5 post-mortem: barriers were
// exposing full load latency to all waves, ~80% of iter time).
// defer-max (THR=8, log2 domain); l via ones-MFMA; Ps wave-private (lgkmcnt only).
__global__ __launch_bounds__(256, 4) void attn_kernel(
    const unsigned short* __restrict__ qT, const unsigned short* __restrict__ kT,
    const unsigned short* __restrict__ vH, const unsigned short* __restrict__ pT,
    float* __restrict__ out)
{
    const int wg = blockIdx.x;
    const int bh = (wg & 7) * 8 + ((wg >> 3) & 7);   // XCD-bijective: 8 (b,h) per XCD
    const int it = wg >> 6;
    const int b = bh >> 2, h = bh & 3;
    const int i0 = it * 64;

    // epilogue transpose buffer; Ps (wave-private P tiles) aliases its storage.
    __shared__ __align__(16) float EpiBuf[64][68];                      // 17408 B
    unsigned short (*Ps)[16][76] = (unsigned short (*)[16][76])EpiBuf;  // 9728 B alias

    const int tid = threadIdx.x;
    const int wid = tid >> 6, lane = tid & 63;
    const int g = lane >> 4, lr = lane & 15;

    const size_t bhNN = (size_t)(b * NH + h) * NN;
    const unsigned short* qTb = qT + bhNN * DH;
    const unsigned short* kTb = kT + bhNN * DH;
    const unsigned short* pTb = pT + (size_t)h * NN * DH;
    const unsigned short* vb  = vH + ((size_t)b * CH + h * DH) * NN;

    // Q-ext A-fragments (registers, whole kernel)
    f16x8 aQ[4];
    {
        const int i = i0 + wid * 16 + lr;
        #pragma unroll
        for (int ks = 0; ks < 4; ++ks) {
            int d = ks * 32 + g * 8;
            const unsigned short* src = (d < 64) ? &qTb[(size_t)i * DH + d]
                                                 : &pTb[(size_t)i * DH + d - 64];
            aQ[ks] = *(const f16x8*)src;
        }
    }

    f16x8 vone;
    #pragma unroll
    for (int e = 0; e < 8; ++e) vone[e] = (_Float16)1.0f;

    const f32x4 z4 = {0.f, 0.f, 0.f, 0.f};
    f32x4 Oacc[4] = {z4, z4, z4, z4};
    f32x4 Lacc = z4;
    float m_run[4];
    #pragma unroll
    for (int r = 0; r < 4; ++r) m_run[r] = -1e30f;

    for (int jt = 0; jt < 16; ++jt) {
        const int jb = jt * 64;

        // ---- QK^T: B-fragments straight from global (L2-hit) ----
        f32x4 S[4] = {z4, z4, z4, z4};
        __builtin_amdgcn_s_setprio(1);
        #pragma unroll
        for (int ks = 0; ks < 4; ++ks) {
            const int dd = ks * 32 + g * 8;
            const unsigned short* kb_ = (dd < 64) ? (kTb + dd) : (qTb + dd - 64);
            f16x8 bf[4];
            #pragma unroll
            for (int fc = 0; fc < 4; ++fc)
                bf[fc] = *(const f16x8*)&kb_[(size_t)(jb + fc * 16 + lr) * DH];
            #pragma unroll
            for (int fc = 0; fc < 4; ++fc)
                S[fc] = __builtin_amdgcn_mfma_f32_16x16x32_f16(aQ[ks], bf[fc], S[fc], 0, 0, 0);
        }
        __builtin_amdgcn_s_setprio(0);

        // ---- V fragments issued now; latency hides under softmax VALU ----
        f16x8 vf[2][4];
        #pragma unroll
        for (int ks = 0; ks < 2; ++ks)
            #pragma unroll
            for (int fc = 0; fc < 4; ++fc)
                vf[ks][fc] = *(const f16x8*)&vb[(size_t)(fc * 16 + lr) * NN + jb + ks * 32 + g * 8];

        // ---- defer-max softmax (log2 domain) ----
        float fm[4], p[4][4];
        #pragma unroll
        for (int r = 0; r < 4; ++r)
            fm[r] = fmaxf(fmaxf(S[0][r], S[1][r]), fmaxf(S[2][r], S[3][r]));
        bool ok = (fm[0] <= m_run[0] + 8.f) && (fm[1] <= m_run[1] + 8.f) &&
                  (fm[2] <= m_run[2] + 8.f) && (fm[3] <= m_run[3] + 8.f);
        if (__all(ok)) {
            // fast path: no cross-lane reduce, no rescale; p <= 2^8 fits fp16
            #pragma unroll
            for (int r = 0; r < 4; ++r)
                #pragma unroll
                for (int fc = 0; fc < 4; ++fc)
                    p[fc][r] = exp2f(S[fc][r] - m_run[r]);
        } else {
            #pragma unroll
            for (int r = 0; r < 4; ++r) {
                float mt = fm[r];
                mt = fmaxf(mt, __shfl_xor(mt, 1));
                mt = fmaxf(mt, __shfl_xor(mt, 2));
                mt = fmaxf(mt, __shfl_xor(mt, 4));
                mt = fmaxf(mt, __shfl_xor(mt, 8));
                float mn = fmaxf(m_run[r], mt);
                float sc = exp2f(m_run[r] - mn);
                m_run[r] = mn;
                #pragma unroll
                for (int fc = 0; fc < 4; ++fc) {
                    Oacc[fc][r] *= sc;
                    p[fc][r] = exp2f(S[fc][r] - mn);
                }
                Lacc[r] *= sc;
            }
        }
        #pragma unroll
        for (int fc = 0; fc < 4; ++fc)
            #pragma unroll
            for (int r = 0; r < 4; ++r)
                Ps[wid][g * 4 + r][fc * 16 + lr] = f2h(p[fc][r]);

        // ---- PV + row-sum (wave-private Ps; compiler inserts lgkmcnt) ----
        __builtin_amdgcn_s_setprio(1);
        #pragma unroll
        for (int ks = 0; ks < 2; ++ks) {
            f16x8 aP = *(const f16x8*)&Ps[wid][lr][ks * 32 + g * 8];
            Lacc = __builtin_amdgcn_mfma_f32_16x16x32_f16(aP, vone, Lacc, 0, 0, 0);
            #pragma unroll
            for (int fc = 0; fc < 4; ++fc)
                Oacc[fc] = __builtin_amdgcn_mfma_f32_16x16x32_f16(aP, vf[ks][fc], Oacc[fc], 0, 0, 0);
        }
        __builtin_amdgcn_s_setprio(0);
    }

    // ---- epilogue: normalize by Lacc, LDS transpose, coalesced store ----
    __syncthreads();    // all waves done with their Ps region before EpiBuf overwrite
    float inv[4];
    #pragma unroll
    for (int r = 0; r < 4; ++r) inv[r] = 1.0f / Lacc[r];
    #pragma unroll
    for (int fc = 0; fc < 4; ++fc)
        #pragma unroll
        for (int r = 0; r < 4; ++r)
            EpiBuf[fc * 16 + lr][wid * 16 + g * 4 + r] = Oacc[fc][r] * inv[r];
    __syncthreads();
    float* ob = out + ((size_t)b * CH + h * DH) * NN + i0;
    #pragma unroll
    for (int rep = 0; rep < 4; ++rep) {
        int f = rep * 256 + tid;
        int r = f >> 4, q4 = f & 15;
        *(float4*)&ob[(size_t)r * NN + q4 * 4] = *(const float4*)&EpiBuf[r][q4 * 4];
    }
}

extern "C" void kernel_launch(void* const* d_in, const int* in_sizes, int n_in,
                              void* d_out, int out_size, void* d_ws, size_t ws_size,
                              hipStream_t stream) {
    const float* x     = (const float*)d_in[0];
    const float* Wq    = (const float*)d_in[1];
    const float* bq    = (const float*)d_in[2];
    const float* Wk    = (const float*)d_in[3];
    const float* bk    = (const float*)d_in[4];
    const float* Wv    = (const float*)d_in[5];
    const float* bv    = (const float*)d_in[6];
    const float* rel_h = (const float*)d_in[7];
    const float* rel_w = (const float*)d_in[8];
    // d_in[9] (reg_qk), d_in[10] (reg_v): dead — reference discards the register-token group.
    float* out = (float*)d_out;

    const size_t SZ = (size_t)BB * NH * NN * DH;        // 4,194,304
    unsigned short* qT = (unsigned short*)d_ws;
    unsigned short* kT = qT + SZ;
    unsigned short* vH = kT + SZ;
    unsigned short* pT = vH + SZ;                       // NH*NN*DH = 262,144
    unsigned short* xT = pT + (size_t)NH * NN * DH;     // BB*NN*CH = 4,194,304
    unsigned short* Wh = xT + SZ;                       // 3*CH*CH = 196,608
    unsigned short* Wl = Wh + (size_t)3 * CH * CH;

    prep_kernel<<<dim3((3 * CH * CH + 255) / 256), 256, 0, stream>>>(Wq, Wk, Wv, Wh, Wl);
    xt_kernel<<<dim3(NN / 32, CH / 32, BB), 256, 0, stream>>>(x, xT);
    pos_kernel<<<dim3((NH * NN * DH + 255) / 256), 256, 0, stream>>>(rel_h, rel_w, pT);
    proj_kernel<<<dim3(NN / 64, CH / 64, BB * 3), 256, 0, stream>>>(
        xT, Wh, Wl, bq, bk, bv, qT, kT, vH);
    attn_kernel<<<dim3(1024), 256, 0, stream>>>(qT, kT, vH, pT, out);
}

// Round 9
// 90.000 us; speedup vs baseline: 2.7450x; 2.7450x over previous
//
#include <hip/hip_runtime.h>

#define BB 16
#define CH 256
#define NH 4
#define DH 64
#define NN 1024

typedef _Float16 f16x8 __attribute__((ext_vector_type(8)));
typedef float f32x4 __attribute__((ext_vector_type(4)));
typedef float f32x16 __attribute__((ext_vector_type(16)));
typedef unsigned int uint32x4 __attribute__((ext_vector_type(4)));

__device__ __forceinline__ unsigned short f2h(float x) {
    _Float16 h = (_Float16)x;
    return __builtin_bit_cast(unsigned short, h);
}

__device__ __forceinline__ unsigned cvtpk(float a, float b) {
    auto r = __builtin_amdgcn_cvt_pkrtz(a, b);      // low half = a, high = b
    return __builtin_bit_cast(unsigned, r);
}

// ---------------- W -> fp16 hi/lo ----------------
__global__ __launch_bounds__(256) void prep_kernel(
    const float* __restrict__ Wq, const float* __restrict__ Wk, const float* __restrict__ Wv,
    unsigned short* __restrict__ Wh, unsigned short* __restrict__ Wl)
{
    int idx = blockIdx.x * 256 + threadIdx.x;   // 3*CH*CH = 196608
    if (idx >= 3 * CH * CH) return;
    int p = idx >> 16, oc = idx & 65535;
    const float* W = (p == 0) ? Wq : ((p == 1) ? Wk : Wv);
    float w = W[oc];
    _Float16 h = (_Float16)w;
    Wh[idx] = __builtin_bit_cast(unsigned short, h);
    Wl[idx] = f2h(w - (float)h);
}

// ---------------- x fp32 [b][c][n] -> xT fp16 [b][n][c] ----------------
__global__ __launch_bounds__(256) void xt_kernel(
    const float* __restrict__ x, unsigned short* __restrict__ xT)
{
    const int b = blockIdx.z, c0 = blockIdx.y * 32, n0 = blockIdx.x * 32;
    __shared__ float T[32][33];
    const int t = threadIdx.x;
    {
        int c = t >> 3, n4 = (t & 7) * 4;
        float4 v4 = *(const float4*)&x[((size_t)b * CH + c0 + c) * NN + n0 + n4];
        T[c][n4 + 0] = v4.x; T[c][n4 + 1] = v4.y;
        T[c][n4 + 2] = v4.z; T[c][n4 + 3] = v4.w;
    }
    __syncthreads();
    {
        int n = t >> 3, c4 = (t & 7) * 4;
        ushort4 o;
        o.x = f2h(T[c4 + 0][n]); o.y = f2h(T[c4 + 1][n]);
        o.z = f2h(T[c4 + 2][n]); o.w = f2h(T[c4 + 3][n]);
        *(ushort4*)&xT[((size_t)b * NN + n0 + n) * CH + c0 + c4] = o;
    }
}

// ---------------- pos^T fp16: pT[h][n][d] ----------------
__global__ __launch_bounds__(256) void pos_kernel(
    const float* __restrict__ rel_h, const float* __restrict__ rel_w,
    unsigned short* __restrict__ pT)
{
    int idx = blockIdx.x * 256 + threadIdx.x;     // NH*NN*DH = 262144
    if (idx >= NH * NN * DH) return;
    int d = idx & 63, n = (idx >> 6) & (NN - 1), h = idx >> 16;
    float val = rel_w[(h * DH + d) * 32 + (n >> 5)] + rel_h[(h * DH + d) * 32 + (n & 31)];
    pT[idx] = f2h(val);
}

// ---------------- projection via fp16 MFMA (W hi/lo 2-pass) ----------------
__global__ __launch_bounds__(256) void proj_kernel(
    const unsigned short* __restrict__ xT,
    const unsigned short* __restrict__ Wh, const unsigned short* __restrict__ Wl,
    const float* __restrict__ bq, const float* __restrict__ bk, const float* __restrict__ bv,
    unsigned short* __restrict__ qT, unsigned short* __restrict__ kT,
    unsigned short* __restrict__ vH)
{
    const int bz = blockIdx.z;
    const int b = bz / 3, p = bz % 3;
    const int n0 = blockIdx.x * 64;
    const int o0 = blockIdx.y * 64;
    const float* bias = (p == 0) ? bq : ((p == 1) ? bk : bv);

    __shared__ __align__(16) unsigned short Xs[64][72];
    __shared__ __align__(16) unsigned short Whs[64][72];
    __shared__ __align__(16) unsigned short Wls[64][72];

    const int tid = threadIdx.x;
    const int wid = tid >> 6, lane = tid & 63;
    const int g = lane >> 4, lr = lane & 15;

    const unsigned short* xb  = xT + (size_t)b * NN * CH;
    const unsigned short* Whp = Wh + (size_t)p * CH * CH;
    const unsigned short* Wlp = Wl + (size_t)p * CH * CH;

    const f32x4 z4 = {0.f, 0.f, 0.f, 0.f};
    f32x4 acc[4] = {z4, z4, z4, z4};

    for (int cs = 0; cs < 4; ++cs) {
        const int c0 = cs * 64;
        __syncthreads();
        #pragma unroll
        for (int rep = 0; rep < 2; ++rep) {
            int f = rep * 256 + tid;
            int r = f >> 3, s = f & 7;
            *(uint4*)&Xs[r][s * 8]  = *(const uint4*)&xb[(size_t)(n0 + r) * CH + c0 + s * 8];
            *(uint4*)&Whs[r][s * 8] = *(const uint4*)&Whp[(size_t)(o0 + r) * CH + c0 + s * 8];
            *(uint4*)&Wls[r][s * 8] = *(const uint4*)&Wlp[(size_t)(o0 + r) * CH + c0 + s * 8];
        }
        __syncthreads();
        #pragma unroll
        for (int ks = 0; ks < 2; ++ks) {
            f16x8 ah = *(const f16x8*)&Whs[wid * 16 + lr][ks * 32 + g * 8];
            f16x8 al = *(const f16x8*)&Wls[wid * 16 + lr][ks * 32 + g * 8];
            #pragma unroll
            for (int fc = 0; fc < 4; ++fc) {
                f16x8 bx = *(const f16x8*)&Xs[fc * 16 + lr][ks * 32 + g * 8];
                acc[fc] = __builtin_amdgcn_mfma_f32_16x16x32_f16(ah, bx, acc[fc], 0, 0, 0);
                acc[fc] = __builtin_amdgcn_mfma_f32_16x16x32_f16(al, bx, acc[fc], 0, 0, 0);
            }
        }
    }

    float bb[4];
    #pragma unroll
    for (int rr = 0; rr < 4; ++rr) bb[rr] = bias[o0 + wid * 16 + g * 4 + rr];

    if (p < 2) {
        const float scale = (p == 0) ? 1.44269504088896f : 1.0f;   // fold log2e into q
        __syncthreads();
        unsigned short (*Os)[72] = Whs;     // reuse as [n-local][o-local]
        #pragma unroll
        for (int fc = 0; fc < 4; ++fc)
            #pragma unroll
            for (int rr = 0; rr < 4; ++rr)
                Os[fc * 16 + lr][wid * 16 + g * 4 + rr] = f2h((acc[fc][rr] + bb[rr]) * scale);
        __syncthreads();
        unsigned short* dst = ((p == 0) ? qT : kT) + ((size_t)(b * NH + blockIdx.y) * NN + n0) * DH;
        #pragma unroll
        for (int rep = 0; rep < 2; ++rep) {
            int f = rep * 256 + tid;
            int r = f >> 3, s = f & 7;
            *(uint4*)&dst[(size_t)r * DH + s * 8] = *(const uint4*)&Os[r][s * 8];
        }
    } else {
        unsigned short* dv = vH + (size_t)b * CH * NN;
        #pragma unroll
        for (int fc = 0; fc < 4; ++fc)
            #pragma unroll
            for (int rr = 0; rr < 4; ++rr) {
                int o = o0 + wid * 16 + g * 4 + rr;
                dv[(size_t)o * NN + n0 + fc * 16 + lr] = f2h(acc[fc][rr] + bb[rr]);
            }
    }
}

// ---------------- fused flash attention: 32x32 swapped-QK^T, in-register softmax ----------------
// S^T[j][i] via mfma_32x32x16(A = K-ext rows j, B = Q-ext cols i): lane(l31,hi) holds
// S^T[j][i=l31] at j = (r&3)+8*(r>>2)+4*hi (C/D layout, HW-verified m74/m101).
//
// ZERO-EXCHANGE PV (replaces R8's permlane construction, which had an unverifiable
// swap-direction dependency): MFMA dot products are invariant to any k-permutation
// applied identically to A and B slots. We DEFINE the PV k-order per 16-group as
//   slot (hi, e) <-> j_local = 4*hi + (e&3) + 8*(e>>2)
// which is exactly what the lane already holds: A-frag = {c[4ksi+0..3]} verbatim.
// V is stored into LDS with the SAME permutation (two b64 stores per 8-j chunk:
// j 8c..8c+3 -> mini-slot 4*(c>>1)+(c&1); j 8c+4..8c+7 -> +2), so the PV B-read
// is a single aligned b128 at 8-slot (js*4+ksi*2+hi) — identical addressing to QK.
//
// K-ext/V double-buffered, 16-slot XOR swizzle; ONE barrier/iter; next-tile global
// loads issued AFTER the barrier so its implicit vmcnt drain never waits on them.
__global__ __launch_bounds__(256, 2) void attn_kernel(
    const unsigned short* __restrict__ qT, const unsigned short* __restrict__ kT,
    const unsigned short* __restrict__ vH, const unsigned short* __restrict__ pT,
    float* __restrict__ out)
{
    const int wg = blockIdx.x;                       // 0..511
    const int bh = (wg & 7) * 8 + ((wg >> 3) & 7);   // XCD-bijective: 8 (b,h) per XCD
    const int it = wg >> 6;                          // 0..7
    const int b = bh >> 2, h = bh & 3;
    const int i0 = it * 128;

    // K: 2 x [64 rows][128 halves] (16KB each). V: 2 x [32 rows][128 halves] (8KB each).
    __shared__ __align__(16) unsigned short KV[24576];      // 48 KB
    __shared__ __align__(16) float Lbuf[128];
    __shared__ float ScBuf[4][32];
    float* Epi = (float*)KV;                                // [64][132] f32 alias (33.8KB)

    const int tid = threadIdx.x;
    const int wid = tid >> 6, lane = tid & 63;
    const int l31 = lane & 31, hi = lane >> 5;

    const size_t bhNN = (size_t)(b * NH + h) * NN;
    const unsigned short* qTb = qT + bhNN * DH;
    const unsigned short* kTb = kT + bhNN * DH;
    const unsigned short* pTb = pT + (size_t)h * NN * DH;
    const unsigned short* vb  = vH + ((size_t)b * CH + h * DH) * NN;

    // Q-ext B-fragments (cols i), loaded once: d = ks*16 + hi*8 + e
    f16x8 bQ[8];
    {
        const int i = i0 + wid * 32 + l31;
        #pragma unroll
        for (int ks = 0; ks < 8; ++ks) {
            int d0 = ks * 16 + hi * 8;
            const unsigned short* src = (d0 < 64) ? &qTb[(size_t)i * DH + d0]
                                                  : &pTb[(size_t)i * DH + d0 - 64];
            bQ[ks] = *(const f16x8*)src;
        }
    }

    const int srow = tid >> 4;       // 0..15
    const int sslot = tid & 15;
    // V store permutation constants (see header comment)
    const int vc = sslot & 7;
    const int vM = ((vc >> 1) << 2) + (vc & 1) + ((sslot & 8) << 1);
    const int vs8 = vM >> 1;
    const int vnib = (vM & 1) * 4;   // halves offset within the 8-slot
    uint4 kst[4], vst[2];

    // coalesced global loads for tile jb (K-ext = [k | q] halves; V rows d)
    #define STAGE_LOAD(jb)                                                                  \
        {                                                                                   \
            _Pragma("unroll")                                                               \
            for (int rep = 0; rep < 4; ++rep) {                                             \
                int row = rep * 16 + srow;                                                  \
                const unsigned short* src = ((sslot < 8) ? kTb : qTb)                       \
                    + (size_t)((jb) + row) * DH + (sslot & 7) * 8;                          \
                kst[rep] = *(const uint4*)src;                                              \
            }                                                                               \
            _Pragma("unroll")                                                               \
            for (int rep = 0; rep < 2; ++rep) {                                             \
                int row = rep * 16 + srow;                                                  \
                int d = row + ((sslot & 8) << 2);                                           \
                vst[rep] = *(const uint4*)&vb[(size_t)d * NN + (jb) + (sslot & 7) * 8];     \
            }                                                                               \
        }

    // swizzled LDS writes into buffer `buf`; V stored j-permuted (2 b64 per chunk)
    #define STAGE_WRITE(buf)                                                                \
        {                                                                                   \
            unsigned short* Kb = KV + (buf) * 8192;                                         \
            unsigned short* Vb = KV + 16384 + (buf) * 4096;                                 \
            _Pragma("unroll")                                                               \
            for (int rep = 0; rep < 4; ++rep) {                                             \
                int row = rep * 16 + srow;                                                  \
                *(uint4*)&Kb[row * 128 + ((sslot ^ (row & 15)) << 3)] = kst[rep];           \
            }                                                                               \
            _Pragma("unroll")                                                               \
            for (int rep = 0; rep < 2; ++rep) {                                             \
                int row = rep * 16 + srow;                                                  \
                uint2 vlo; vlo.x = vst[rep].x; vlo.y = vst[rep].y;                          \
                uint2 vhi2; vhi2.x = vst[rep].z; vhi2.y = vst[rep].w;                       \
                *(uint2*)&Vb[row * 128 + ((vs8 ^ (row & 15)) << 3) + vnib] = vlo;           \
                *(uint2*)&Vb[row * 128 + (((vs8 + 1) ^ (row & 15)) << 3) + vnib] = vhi2;    \
            }                                                                               \
        }

    f32x16 O0 = {}, O1 = {};
    float m_run = -1e30f, l_run = 0.f;

    STAGE_LOAD(0);
    STAGE_WRITE(0);

    for (int t = 0; t < 16; ++t) {
        __syncthreads();                    // buf[t&1] visible to all waves
        if (t < 15) STAGE_LOAD((t + 1) * 64);   // after barrier: hidden under compute

        const unsigned short* Kb = KV + (t & 1) * 8192;
        const unsigned short* Vb = KV + 16384 + (t & 1) * 4096;

        // ---- QK^T (swapped): two 32x32 S^T subtiles ----
        f32x16 s0 = {}, s1 = {};
        __builtin_amdgcn_s_setprio(1);
        #pragma unroll
        for (int ks = 0; ks < 8; ++ks) {
            int r0 = l31, r1 = 32 + l31;
            int slot = ks * 2 + hi;
            f16x8 a0 = *(const f16x8*)&Kb[r0 * 128 + ((slot ^ (r0 & 15)) << 3)];
            f16x8 a1 = *(const f16x8*)&Kb[r1 * 128 + ((slot ^ (r1 & 15)) << 3)];
            s0 = __builtin_amdgcn_mfma_f32_32x32x16_f16(a0, bQ[ks], s0, 0, 0, 0);
            s1 = __builtin_amdgcn_mfma_f32_32x32x16_f16(a1, bQ[ks], s1, 0, 0, 0);
        }
        __builtin_amdgcn_s_setprio(0);

        // ---- defer-max online softmax (log2 domain), fully in-lane ----
        float fm = s0[0];
        #pragma unroll
        for (int r = 1; r < 16; ++r) fm = fmaxf(fm, s0[r]);
        #pragma unroll
        for (int r = 0; r < 16; ++r) fm = fmaxf(fm, s1[r]);

        if (!__all(fm <= m_run + 8.f)) {
            float fmf = fmaxf(fm, __shfl_xor(fm, 32));   // pair-lane: full row max
            float mn = fmaxf(m_run, fmf);
            float sc = exp2f(m_run - mn);
            m_run = mn;
            l_run *= sc;
            if (lane < 32) ScBuf[wid][lane] = sc;        // sc for softmax row i = lane
            #pragma unroll
            for (int r = 0; r < 16; ++r) {
                int irow = (r & 3) + 8 * (r >> 2) + 4 * hi;
                float scv = ScBuf[wid][irow];
                O0[r] *= scv; O1[r] *= scv;
            }
        }

        // ---- P = exp2(S - m): pack fp16 pairs, sum in-lane ----
        unsigned c0[8], c1[8];
        float ps = 0.f;
        #pragma unroll
        for (int m = 0; m < 8; ++m) {
            float pa = exp2f(s0[2 * m]     - m_run);
            float pb = exp2f(s0[2 * m + 1] - m_run);
            float pc = exp2f(s1[2 * m]     - m_run);
            float pd = exp2f(s1[2 * m + 1] - m_run);
            ps += (pa + pb) + (pc + pd);
            c0[m] = cvtpk(pa, pb);
            c1[m] = cvtpk(pc, pd);
        }
        l_run += ps;

        // ---- PV A-frags: lane's own words, zero exchange (k-order is permuted;
        //      V was stored with the same permutation) ----
        f16x8 pA[2][2];
        #pragma unroll
        for (int js = 0; js < 2; ++js) {
            unsigned* c = js ? c1 : c0;
            #pragma unroll
            for (int ksi = 0; ksi < 2; ++ksi) {
                uint32x4 w = { c[ksi * 4 + 0], c[ksi * 4 + 1], c[ksi * 4 + 2], c[ksi * 4 + 3] };
                pA[js][ksi] = __builtin_bit_cast(f16x8, w);
            }
        }

        // ---- PV: O[i][d] += P * V  (V B-frags from permuted+swizzled Vb) ----
        __builtin_amdgcn_s_setprio(1);
        #pragma unroll
        for (int js = 0; js < 2; ++js) {
            #pragma unroll
            for (int ksi = 0; ksi < 2; ++ksi) {
                int rv = l31;
                int sl0 = (js * 4 + ksi * 2 + hi) ^ (rv & 15);
                int sl1 = (8 + js * 4 + ksi * 2 + hi) ^ (rv & 15);
                f16x8 v0 = *(const f16x8*)&Vb[rv * 128 + (sl0 << 3)];
                f16x8 v1 = *(const f16x8*)&Vb[rv * 128 + (sl1 << 3)];
                O0 = __builtin_amdgcn_mfma_f32_32x32x16_f16(pA[js][ksi], v0, O0, 0, 0, 0);
                O1 = __builtin_amdgcn_mfma_f32_32x32x16_f16(pA[js][ksi], v1, O1, 0, 0, 0);
            }
        }
        __builtin_amdgcn_s_setprio(0);

        if (t < 15) STAGE_WRITE((t + 1) & 1);    // vmcnt wait lands here, post-compute
    }

    // ---- epilogue: pair-sum l, LDS transpose, normalized coalesced store ----
    float l_full = l_run + __shfl_xor(l_run, 32);
    float invl = 1.0f / l_full;
    __syncthreads();                      // done reading KV before Epi overwrite
    if (lane < 32) Lbuf[wid * 32 + lane] = invl;
    #pragma unroll
    for (int r = 0; r < 16; ++r) {
        int irow = (r & 3) + 8 * (r >> 2) + 4 * hi;
        int ilocal = wid * 32 + irow;
        Epi[(l31) * 132 + ilocal]      = O0[r];
        Epi[(32 + l31) * 132 + ilocal] = O1[r];
    }
    __syncthreads();
    float* ob = out + ((size_t)b * CH + h * DH) * NN + i0;
    #pragma unroll
    for (int rep = 0; rep < 8; ++rep) {
        int f = rep * 256 + tid;
        int d = f >> 5, q = f & 31;
        float4 v4 = *(const float4*)&Epi[d * 132 + q * 4];
        float4 iv = *(const float4*)&Lbuf[q * 4];
        v4.x *= iv.x; v4.y *= iv.y; v4.z *= iv.z; v4.w *= iv.w;
        *(float4*)&ob[(size_t)d * NN + q * 4] = v4;
    }
}

extern "C" void kernel_launch(void* const* d_in, const int* in_sizes, int n_in,
                              void* d_out, int out_size, void* d_ws, size_t ws_size,
                              hipStream_t stream) {
    const float* x     = (const float*)d_in[0];
    const float* Wq    = (const float*)d_in[1];
    const float* bq    = (const float*)d_in[2];
    const float* Wk    = (const float*)d_in[3];
    const float* bk    = (const float*)d_in[4];
    const float* Wv    = (const float*)d_in[5];
    const float* bv    = (const float*)d_in[6];
    const float* rel_h = (const float*)d_in[7];
    const float* rel_w = (const float*)d_in[8];
    // d_in[9] (reg_qk), d_in[10] (reg_v): dead — reference discards the register-token group.
    float* out = (float*)d_out;

    const size_t SZ = (size_t)BB * NH * NN * DH;        // 4,194,304
    unsigned short* qT = (unsigned short*)d_ws;
    unsigned short* kT = qT + SZ;
    unsigned short* vH = kT + SZ;
    unsigned short* pT = vH + SZ;                       // NH*NN*DH = 262,144
    unsigned short* xT = pT + (size_t)NH * NN * DH;     // BB*NN*CH = 4,194,304
    unsigned short* Wh = xT + SZ;                       // 3*CH*CH = 196,608
    unsigned short* Wl = Wh + (size_t)3 * CH * CH;

    prep_kernel<<<dim3((3 * CH * CH + 255) / 256), 256, 0, stream>>>(Wq, Wk, Wv, Wh, Wl);
    xt_kernel<<<dim3(NN / 32, CH / 32, BB), 256, 0, stream>>>(x, xT);
    pos_kernel<<<dim3((NH * NN * DH + 255) / 256), 256, 0, stream>>>(rel_h, rel_w, pT);
    proj_kernel<<<dim3(NN / 64, CH / 64, BB * 3), 256, 0, stream>>>(
        xT, Wh, Wl, bq, bk, bv, qT, kT, vH);
    attn_kernel<<<dim3(512), 256, 0, stream>>>(qT, kT, vH, pT, out);
}